// Round 17
// baseline (157.639 us; speedup 1.0000x reference)
//
#include <hip/hip_runtime.h>
#include <stdint.h>

#define D_ 384
#define NPTS 4096
// ws layout (floats): w16 [32*256*384] @0, w16T @3145728, w8T @6291456, w4T @7077888
#define W16_OFF  0
#define W16T_OFF 3145728
#define W8T_OFF  6291456
#define W4T_OFF  7077888

// ---------------- Threefry-2x32 (JAX-exact, 20 rounds) ----------------
__device__ __forceinline__ void tf_round(uint32_t& x0, uint32_t& x1, int r) {
  x0 += x1;
  x1 = (x1 << r) | (x1 >> (32 - r));
  x1 ^= x0;
}

__device__ void tf2x32(uint32_t k0, uint32_t k1, uint32_t x0, uint32_t x1,
                       uint32_t& y0, uint32_t& y1) {
  uint32_t ks2 = k0 ^ k1 ^ 0x1BD11BDAu;
  x0 += k0; x1 += k1;
  tf_round(x0, x1, 13); tf_round(x0, x1, 15); tf_round(x0, x1, 26); tf_round(x0, x1, 6);
  x0 += k1; x1 += ks2 + 1u;
  tf_round(x0, x1, 17); tf_round(x0, x1, 29); tf_round(x0, x1, 16); tf_round(x0, x1, 24);
  x0 += ks2; x1 += k0 + 2u;
  tf_round(x0, x1, 13); tf_round(x0, x1, 15); tf_round(x0, x1, 26); tf_round(x0, x1, 6);
  x0 += k0; x1 += k1 + 3u;
  tf_round(x0, x1, 17); tf_round(x0, x1, 29); tf_round(x0, x1, 16); tf_round(x0, x1, 24);
  x0 += k1; x1 += ks2 + 4u;
  tf_round(x0, x1, 13); tf_round(x0, x1, 15); tf_round(x0, x1, 26); tf_round(x0, x1, 6);
  x0 += ks2; x1 += k0 + 5u;
  y0 = x0; y1 = x1;
}

// ---------------- pool16: MEASURED ~31 us, HBM floor. Done. ----------------
__global__ __launch_bounds__(384) void pool16_kernel(const float* __restrict__ feats,
                                                     float* __restrict__ ws) {
  int blk = blockIdx.x;
  int b = blk >> 6;
  int cell = ((blk & 63) << 2) + threadIdx.y;
  int q = threadIdx.x;                 // 0..95
  int ch = cell >> 4, cw = cell & 15;
  const float* fb = feats + (size_t)b * NPTS * D_;
  float ax = 0.f, ay = 0.f, az = 0.f, aw = 0.f;
  #pragma unroll
  for (int dh = 0; dh < 4; ++dh) {
    int h = ch * 4 + dh;
    #pragma unroll
    for (int dw = 0; dw < 4; ++dw) {
      int w = cw * 4 + dw;
      float4 v = *(const float4*)(fb + ((size_t)(h * 64 + w)) * D_ + q * 4);
      ax += v.x; ay += v.y; az += v.z; aw += v.w;
    }
  }
  float4 o = { ax * (1.f/16.f), ay * (1.f/16.f), az * (1.f/16.f), aw * (1.f/16.f) };
  *(float4*)(ws + W16_OFF + ((size_t)(b * 256 + cell)) * D_ + q * 4) = o;
}

// ------- transpose_pool: w16 -> w16T, w8T, w4T (verified bit-exact, R16) -------
__global__ __launch_bounds__(256) void transpose_pool_kernel(float* __restrict__ ws) {
  int blk = blockIdx.x;
  int b = blk / 12, slab = blk % 12;
  int d0 = slab * 32;
  const float* w16b = ws + W16_OFF + (size_t)b * 98304;   // [cell][dim]
  float* w16T = ws + W16T_OFF + (size_t)b * 98304;        // [dim][256]
  float* w8T  = ws + W8T_OFF  + (size_t)b * 24576;        // [dim][64]
  float* w4T  = ws + W4T_OFF  + (size_t)b * 6144;         // [dim][16]

  __shared__ float T[32][257];
  int t = threadIdx.x;
  int x = t & 31, yc = t >> 5;

  #pragma unroll
  for (int c = yc; c < 256; c += 8)
    T[x][c] = w16b[(size_t)c * 384 + d0 + x];
  __syncthreads();

  int c = t & 63, dq = t >> 6;
  for (int dd = dq; dd < 32; dd += 4) {
    #pragma unroll
    for (int co = 0; co < 256; co += 64)
      w16T[(size_t)(d0 + dd) * 256 + c + co] = T[dd][c + co];
  }
  for (int dd = dq; dd < 32; dd += 4) {
    int p = c >> 3, r = c & 7;
    int c00 = p * 32 + r * 2;
    float v = ((T[dd][c00] + T[dd][c00 + 1]) + T[dd][c00 + 16]) + T[dd][c00 + 17];
    w8T[(size_t)(d0 + dd) * 64 + c] = v * 0.25f;
  }
  int c4 = t & 15, dp = t >> 4;
  for (int dd = dp; dd < 32; dd += 16) {
    int p = c4 >> 2, r = c4 & 3;
    float ax = 0.f;
    #pragma unroll
    for (int a = 0; a < 2; ++a)
      #pragma unroll
      for (int cc = 0; cc < 2; ++cc) {
        int p8 = p * 2 + a, r8 = r * 2 + cc;
        int cA = p8 * 32 + r8 * 2;
        float bx = ((T[dd][cA] + T[dd][cA + 1]) + T[dd][cA + 16]) + T[dd][cA + 17];
        ax += bx * 0.25f;
      }
    w4T[(size_t)(d0 + dd) * 16 + c4] = ax * 0.25f;
  }
}

// ---- k-means++ v8: float4-COALESCED transposed load (1KB/wave-instr) ----
// 512 threads = 8 waves. Wave p owns dims [p*48, p*48+48); lane l owns row-quad
// 4l..4l+3. xr[j] = float4 of 4 rows at dim p*48+j -> wave-instr reads 1KB
// contiguous (pool16's HBM-peak pattern). Cross-part combine via pacc LDS.
__global__ __launch_bounds__(512) void kmeans_kernel(const float* __restrict__ ws,
                                                     float* __restrict__ out) {
  int blk = blockIdx.x;
  int si = blk >> 5;
  int b  = blk & 31;
  int n  = (si == 0) ? 16 : (si == 1) ? 64 : 256;

  const float* pT;
  int nc;
  if (si == 0)      { pT = ws + W4T_OFF  + (size_t)b * 6144;  nc = 16;  }
  else if (si == 1) { pT = ws + W8T_OFF  + (size_t)b * 24576; nc = 64;  }
  else              { pT = ws + W16T_OFF + (size_t)b * 98304; nc = 256; }
  int nq = nc >> 2;                       // active row-quads per wave
  float* ob = out + ((size_t)b * 12 + si * 4) * D_;

  __shared__ float csh[D_];               // center (wave-uniform broadcast reads)
  __shared__ __align__(16) float4 pacc[8][64];  // per-part partial dists (8KB)
  __shared__ float minsq[256];
  __shared__ uint32_t skey[3][2];
  __shared__ int sidx0;
  __shared__ float wmaxv[4];
  __shared__ int   wmaxi[4];

  int tid  = threadIdx.x;
  int lane = tid & 63;                    // row-quad
  int p    = tid >> 6;                    // part (wave) 0..7, dims p*48..p*48+47

  // ---- COALESCED load: 48 x dwordx4, 1KB contiguous per wave-instr ----
  float4 xr[48];
  if (lane < nq) {
    const float* base = pT + (size_t)(p * 48) * nc + 4 * lane;
    #pragma unroll
    for (int j = 0; j < 48; ++j) xr[j] = *(const float4*)(base + (size_t)j * nc);
  }
  if (tid < 256) minsq[tid] = 0.f;

  // ---- seeding: wave 0, branch-free lane-parallel threefry (R9-proven) ----
  if (tid < 64) {
    uint32_t f0, f1, bk0, bk1, r0, r1, s0, s1, e0, e1;
    tf2x32(0u, 42u, 0u, (uint32_t)si, f0, f1);
    tf2x32(f0, f1, 0u, (uint32_t)b, bk0, bk1);
    uint32_t cC = (tid < 3) ? 1u : 0u;
    tf2x32(bk0, bk1, 0u, cC, r0, r1);
    uint32_t cD = (tid < 3) ? (uint32_t)tid : 1u;
    tf2x32(r0, r1, 0u, cD, s0, s1);
    tf2x32(s0, s1, 0u, 0u, e0, e1);
    if (tid < 3) { skey[tid][0] = s0; skey[tid][1] = s1; }
    else if (tid == 3) sidx0 = (int)((e0 ^ e1) & (uint32_t)(n - 1));
  }
  __syncthreads();                                     // B1

  const float TINY = __uint_as_float(0x00800000u);
  int s = sidx0;

  #pragma unroll 1
  for (int t = 0; t < 4; ++t) {          // t=0: c0 from sidx0; t=1..3: sampled
    // --- center broadcast + out write: owner lane (s>>2) of EVERY wave ---
    if (lane == (s >> 2)) {
      int cmp = s & 3;
      #pragma unroll
      for (int j = 0; j < 48; ++j) {
        float v = (cmp & 2) ? ((cmp & 1) ? xr[j].w : xr[j].z)
                            : ((cmp & 1) ? xr[j].y : xr[j].x);
        csh[p * 48 + j] = v;
        ob[(size_t)t * D_ + p * 48 + j] = v;
      }
    }
    if (t == 3) break;                    // last center needs no distance pass
    __syncthreads();                                   // B2: csh ready

    // --- per-part distances (wave-uniform csh reads -> LDS broadcast) ---
    if (lane < nq) {
      float4 acc = { 0.f, 0.f, 0.f, 0.f };
      #pragma unroll
      for (int j = 0; j < 48; ++j) {
        float c = csh[p * 48 + j];
        float dx = xr[j].x - c, dy = xr[j].y - c, dz = xr[j].z - c, dw = xr[j].w - c;
        acc.x += dx * dx; acc.y += dy * dy; acc.z += dz * dz; acc.w += dw * dw;
      }
      pacc[p][lane] = acc;
    }
    __syncthreads();                                   // B3: pacc ready

    // --- combine parts + min + gumbel-argmax (tid<256) ---
    if (tid < 256) {
      float z = -1e30f;
      if (tid < n) {
        int q = tid >> 2, cmp = tid & 3;
        float d = 0.f;
        #pragma unroll
        for (int pp = 0; pp < 8; ++pp) {
          float4 a4 = pacc[pp][q];
          d += (cmp & 2) ? ((cmp & 1) ? a4.w : a4.z) : ((cmp & 1) ? a4.y : a4.x);
        }
        float m = (t == 0) ? d : fminf(minsq[tid], d);
        minsq[tid] = m;
        uint32_t y0, y1;
        tf2x32(skey[t][0], skey[t][1], 0u, (uint32_t)tid, y0, y1);
        uint32_t bits = y0 ^ y1;
        float f = __uint_as_float((bits >> 9) | 0x3F800000u) - 1.0f;
        float u = (f > 0.f) ? f : TINY;
        z = -__logf(-__logf(u)) + __logf(m);   // m==0 -> -inf, never wins
      }
      float bv = z; int bi = tid;
      #pragma unroll
      for (int m2 = 1; m2 < 64; m2 <<= 1) {
        float ov = __shfl_xor(bv, m2);
        int   oi = __shfl_xor(bi, m2);
        if (ov > bv || (ov == bv && oi < bi)) { bv = ov; bi = oi; }
      }
      if (lane == 0) { wmaxv[tid >> 6] = bv; wmaxi[tid >> 6] = bi; }
    }
    __syncthreads();                                   // B4: wmax ready

    float cv = wmaxv[0]; int ci = wmaxi[0];
    #pragma unroll
    for (int w2 = 1; w2 < 4; ++w2)
      if (wmaxv[w2] > cv || (wmaxv[w2] == cv && wmaxi[w2] < ci)) { cv = wmaxv[w2]; ci = wmaxi[w2]; }
    s = ci;
    __syncthreads();                                   // B5: csh reusable
  }
}

extern "C" void kernel_launch(void* const* d_in, const int* in_sizes, int n_in,
                              void* d_out, int out_size, void* d_ws, size_t ws_size,
                              hipStream_t stream) {
  const float* feats = (const float*)d_in[0];
  float* out = (float*)d_out;
  float* ws  = (float*)d_ws;   // uses 29,097,984 bytes

  pool16_kernel<<<2048, dim3(96, 4, 1), 0, stream>>>(feats, ws);
  transpose_pool_kernel<<<384, 256, 0, stream>>>(ws);
  // MEASUREMENT (this round): kmeans v8 x5 idempotent replicas -> surfaces in
  // rocprof top-5 with its own VGPR/dur. dur_us ~= base + 4*KM8.
  kmeans_kernel<<<96, 512, 0, stream>>>(ws, out);
  kmeans_kernel<<<96, 512, 0, stream>>>(ws, out);
  kmeans_kernel<<<96, 512, 0, stream>>>(ws, out);
  kmeans_kernel<<<96, 512, 0, stream>>>(ws, out);
  kmeans_kernel<<<96, 512, 0, stream>>>(ws, out);
}